// Round 4
// baseline (699.156 us; speedup 1.0000x reference)
//
#include <hip/hip_runtime.h>
#include <hip/hip_fp16.h>
#include <stdint.h>

#define S_DIM 64
#define L_DIM 64
#define B_DIM 16
#define LB    1024      // L*B
#define DIN   1024
#define DA    512
#define M_TOT 65536     // S*LB

using f16x8 = __attribute__((ext_vector_type(8))) _Float16;
using f32x4 = __attribute__((ext_vector_type(4))) float;

typedef const __attribute__((address_space(1))) void* gas_ptr;
typedef __attribute__((address_space(3))) void* las_ptr;

__device__ __forceinline__ void load_lds16(const void* g, void* l) {
    __builtin_amdgcn_global_load_lds((gas_ptr)g, (las_ptr)l, 16, 0, 0);
}

__device__ __forceinline__ float fast_tanh(float x) {
    return 1.0f - 2.0f / (__expf(2.0f * x) + 1.0f);
}

// ---------------- K0: convert Wc, Wq, query to fp16 in workspace -----------
__global__ void cvt_all(const float* __restrict__ Wc, const float* __restrict__ Wq,
                        const float* __restrict__ q,
                        _Float16* __restrict__ Wch, _Float16* __restrict__ Wqh,
                        _Float16* __restrict__ Qh) {
    int i = blockIdx.x * 256 + threadIdx.x;
    if (i < DA * DIN)            Wch[i] = (_Float16)Wc[i];
    else if (i < 2 * DA * DIN)   Wqh[i - DA * DIN] = (_Float16)Wq[i - DA * DIN];
    else                         Qh[i - 2 * DA * DIN] = (_Float16)q[i - 2 * DA * DIN];
}

// ---------------- K1: qp'[lb][n] = query@Wq^T + bq + bc --------------------
__global__ __launch_bounds__(256) void qp_gemm(
    const _Float16* __restrict__ Qh,    // [LB][DIN]
    const _Float16* __restrict__ Wqh,   // [DA][DIN]
    const float* __restrict__ bq, const float* __restrict__ bc,
    float* __restrict__ qp)             // [LB][DA]
{
    __shared__ __align__(16) _Float16 lA[64 * 64];
    __shared__ __align__(16) _Float16 lB[64 * 64];
    const int t = threadIdx.x;
    const int w = t >> 6, lane = t & 63;
    const int quad = lane >> 4, m16 = lane & 15;
    const int n0 = blockIdx.x * 64, lb0 = blockIdx.y * 64;

    f32x4 acc[4] = {};

    for (int kt = 0; kt < DIN / 64; ++kt) {
#pragma unroll
        for (int i = 0; i < 2; ++i) {
            int c = (w * 2 + i) * 64 + lane;
            int row = c >> 3;
            int kc = (c & 7) ^ (row & 7);
            load_lds16(Qh  + (size_t)(lb0 + row) * DIN + kt * 64 + kc * 8, (char*)lA + (size_t)c * 16);
            load_lds16(Wqh + (size_t)(n0  + row) * DIN + kt * 64 + kc * 8, (char*)lB + (size_t)c * 16);
        }
        __syncthreads();
#pragma unroll
        for (int kk = 0; kk < 64; kk += 32) {
            int cq = (kk >> 3) + quad;
            int ar = 16 * w + m16;
            f16x8 a = *(const f16x8*)((const char*)lA + ar * 128 + ((cq ^ (ar & 7)) * 16));
#pragma unroll
            for (int j = 0; j < 4; ++j) {
                int br = 16 * j + m16;
                f16x8 b = *(const f16x8*)((const char*)lB + br * 128 + ((cq ^ (br & 7)) * 16));
                acc[j] = __builtin_amdgcn_mfma_f32_16x16x32_f16(a, b, acc[j], 0, 0, 0);
            }
        }
        __syncthreads();
    }
#pragma unroll
    for (int j = 0; j < 4; ++j) {
        int n = n0 + 16 * j + m16;
        float bias = bq[n] + bc[n];
#pragma unroll
        for (int r = 0; r < 4; ++r) {
            int lb = lb0 + 16 * w + quad * 4 + r;
            qp[(size_t)lb * DA + n] = acc[j][r] + bias;
        }
    }
}

// ---------------- K2: score GEMM, 128m x 512n (full N), B double-buffered --
// 256 threads / 4 waves; each wave: all 128 m-rows x its 128 n-slice.
// acc = 8x8 f32x4 = 256 regs/wave -> 1 wave/SIMD (launch_bounds (256,1)).
// LDS: A 16 KB (single) + B 2x64 KB (dbuf) + lP 2 KB = 146 KB (gfx950: 160).
// Per iter: [b1] cvt/ds_write A(kt) [b2] issue B-DMA(kt+1)+A-loads(kt+1)
//           -> MFMA(kt). Prefetches drain at next b1, hidden by MFMA stage.
__global__ __launch_bounds__(256, 1) void score_gemm4(
    const float* __restrict__ ctx,      // [M_TOT][DIN] fp32
    const _Float16* __restrict__ Wch,   // [DA][DIN]
    const float* __restrict__ qp,       // [LB][DA]
    const float* __restrict__ v,        // [DA]
    float* __restrict__ sc)             // [M_TOT]
{
    __shared__ __align__(16) _Float16 lA[128 * 64];       // 16 KB
    __shared__ __align__(16) _Float16 lB[2][512 * 64];    // 128 KB
    __shared__ float lP[4][128];                          // 2 KB

    const int t = threadIdx.x;
    const int w = t >> 6, lane = t & 63;
    const int quad = lane >> 4, m16 = lane & 15;
    const int m0 = blockIdx.x * 128;

    f32x4 acc[8][8] = {};                                 // 256 regs

    const int arow = t >> 1;                              // 0..127
    const int acol = t & 1;                               // 32-float half
    const float* gA = ctx + (size_t)(m0 + arow) * DIN + acol * 32;

    // ---- prologue: B(0) DMA + A(0) loads ----
#pragma unroll
    for (int i = 0; i < 16; ++i) {
        int c = (w * 16 + i) * 64 + lane;                 // 0..4095
        int row = c >> 3;                                 // 0..511
        int kc = (c & 7) ^ (row & 7);
        load_lds16(Wch + (size_t)row * DIN + kc * 8, (char*)lB[0] + (size_t)c * 16);
    }
    f32x4 fA[8];
#pragma unroll
    for (int qd = 0; qd < 8; ++qd) fA[qd] = *(const f32x4*)(gA + qd * 4);

#pragma unroll 1
    for (int kt = 0; kt < DIN / 64; ++kt) {
        if (kt) __syncthreads();                          // b1: drains B(kt)/A(kt)
        // cvt A(kt) regs -> swizzled ds_write_b128
#pragma unroll
        for (int q2 = 0; q2 < 4; ++q2) {
            f16x8 h = {(_Float16)fA[2*q2][0], (_Float16)fA[2*q2][1],
                       (_Float16)fA[2*q2][2], (_Float16)fA[2*q2][3],
                       (_Float16)fA[2*q2+1][0], (_Float16)fA[2*q2+1][1],
                       (_Float16)fA[2*q2+1][2], (_Float16)fA[2*q2+1][3]};
            int c = acol * 4 + q2;
            *(f16x8*)((char*)lA + arow * 128 + ((c ^ (arow & 7)) * 16)) = h;
        }
        __syncthreads();                                  // b2: cheap (lgkm only)
        // prefetch B(kt+1) + A(kt+1): fly across MFMA(kt)
        if (kt < DIN / 64 - 1) {
            const _Float16* gB = Wch + (kt + 1) * 64;
            char* dB = (char*)lB[(kt + 1) & 1];
#pragma unroll
            for (int i = 0; i < 16; ++i) {
                int c = (w * 16 + i) * 64 + lane;
                int row = c >> 3;
                int kc = (c & 7) ^ (row & 7);
                load_lds16(gB + (size_t)row * DIN + kc * 8, dB + (size_t)c * 16);
            }
            const float* p = gA + (kt + 1) * 64;
#pragma unroll
            for (int qd = 0; qd < 8; ++qd) fA[qd] = *(const f32x4*)(p + qd * 4);
        }
        // MFMA(kt)
        const char* bbuf = (const char*)lB[kt & 1];
#pragma unroll
        for (int kk = 0; kk < 64; kk += 32) {
            int cq = (kk >> 3) + quad;
            f16x8 a[8], b[8];
#pragma unroll
            for (int i = 0; i < 8; ++i) {
                int ar = 16 * i + m16;
                a[i] = *(const f16x8*)((const char*)lA + ar * 128 + ((cq ^ (ar & 7)) * 16));
            }
#pragma unroll
            for (int j = 0; j < 8; ++j) {
                int br = w * 128 + 16 * j + m16;
                b[j] = *(const f16x8*)(bbuf + br * 128 + ((cq ^ (br & 7)) * 16));
            }
#pragma unroll
            for (int i = 0; i < 8; ++i)
#pragma unroll
                for (int j = 0; j < 8; ++j)
                    acc[i][j] = __builtin_amdgcn_mfma_f32_16x16x32_f16(a[i], b[j], acc[i][j], 0, 0, 0);
        }
    }

    // ---- epilogue: tanh(cp + qp')*v, full-n reduction in-block ----
    float vv[8];
    int nn[8];
#pragma unroll
    for (int j = 0; j < 8; ++j) { nn[j] = w * 128 + 16 * j + m16; vv[j] = v[nn[j]]; }

    float part[32];
#pragma unroll
    for (int i = 0; i < 8; ++i) {
#pragma unroll
        for (int r = 0; r < 4; ++r) {
            int gm = m0 + 16 * i + quad * 4 + r;
            int lb = gm & (LB - 1);
            const float* qrow = qp + (size_t)lb * DA;
            float s = 0.f;
#pragma unroll
            for (int j = 0; j < 8; ++j) {
                float x = acc[i][j][r] + qrow[nn[j]];
                s += fast_tanh(x) * vv[j];
            }
            part[i * 4 + r] = s;
        }
    }
#pragma unroll
    for (int off = 1; off < 16; off <<= 1) {
#pragma unroll
        for (int k = 0; k < 32; ++k) part[k] += __shfl_xor(part[k], off, 64);
    }
    if (m16 == 0) {
#pragma unroll
        for (int k = 0; k < 32; ++k) {
            int row_local = 16 * (k >> 2) + quad * 4 + (k & 3);
            lP[w][row_local] = part[k];
        }
    }
    __syncthreads();
    if (t < 128) {
        sc[m0 + t] = lP[0][t] + lP[1][t] + lP[2][t] + lP[3][t];
    }
}

// ---------------- K3: fused softmax (over s) + weighted sum ----------------
__global__ __launch_bounds__(256) void softmax_ws(
    const float* __restrict__ sc, const int* __restrict__ mask,
    const float* __restrict__ ctx,
    float* __restrict__ alpha_out, float* __restrict__ attn_out) {
    __shared__ float lAl[S_DIM];
    const int lb = blockIdx.x;
    const int t = threadIdx.x;
    if (t < S_DIM) {
        int s = t;
        int idx = s * LB + lb;
        float x = sc[idx];
        if (mask[idx] == 0) x = -1e9f;
        float mx = x;
#pragma unroll
        for (int off = 1; off < 64; off <<= 1) mx = fmaxf(mx, __shfl_xor(mx, off, 64));
        float e = __expf(x - mx);
        float sum = e;
#pragma unroll
        for (int off = 1; off < 64; off <<= 1) sum += __shfl_xor(sum, off, 64);
        float a = e / sum;
        alpha_out[idx] = a;
        lAl[s] = a;
    }
    __syncthreads();
    f32x4 acc = {0.f, 0.f, 0.f, 0.f};
    const float* base = ctx + (size_t)lb * DIN + t * 4;
#pragma unroll 4
    for (int s = 0; s < S_DIM; ++s) {
        float a = lAl[s];
        f32x4 c = *(const f32x4*)(base + (size_t)s * LB * DIN);
        acc += a * c;
    }
    *(f32x4*)(attn_out + (size_t)lb * DIN + t * 4) = acc;
}

extern "C" void kernel_launch(void* const* d_in, const int* in_sizes, int n_in,
                              void* d_out, int out_size, void* d_ws, size_t ws_size,
                              hipStream_t stream) {
    (void)in_sizes; (void)n_in; (void)out_size; (void)ws_size;
    const float* ctx   = (const float*)d_in[0];
    const float* query = (const float*)d_in[1];
    const int*   mask  = (const int*)d_in[2];
    const float* Wc    = (const float*)d_in[3];
    const float* bc    = (const float*)d_in[4];
    const float* Wq    = (const float*)d_in[5];
    const float* bq    = (const float*)d_in[6];
    const float* v     = (const float*)d_in[7];

    float* out_attn  = (float*)d_out;                       // [LB][DIN]
    float* out_alpha = (float*)d_out + (size_t)LB * DIN;    // [S][LB]

    char* ws = (char*)d_ws;
    _Float16* Wch = (_Float16*)(ws);                        // 1 MB
    _Float16* Wqh = (_Float16*)(ws + (1 << 20));            // 1 MB
    _Float16* Qh  = (_Float16*)(ws + (2 << 20));            // 2 MB
    float*    qp  = (float*)(ws + (4 << 20));               // 2 MB
    float*    sc  = (float*)(ws + (6 << 20));               // 256 KB

    cvt_all<<<(2 * DA * DIN + LB * DIN) / 256, 256, 0, stream>>>(Wc, Wq, query, Wch, Wqh, Qh);
    qp_gemm<<<dim3(DA / 64, LB / 64), 256, 0, stream>>>(Qh, Wqh, bq, bc, qp);
    score_gemm4<<<M_TOT / 128, 256, 0, stream>>>(ctx, Wch, qp, v, sc);
    softmax_ws<<<LB, 256, 0, stream>>>(sc, mask, ctx, out_alpha, out_attn);
}